// Round 8
// baseline (476.747 us; speedup 1.0000x reference)
//
#include <hip/hip_runtime.h>
#include <hip/hip_bf16.h>

// out = tril((2Q - tril(QK^T)K) K^T) V per (b,h): two fused causal passes of
// Y = tril(X K^T) W  (pass0: X=Q,W=K -> o2; pass1: X=2Q-o2, W=V).
// R8 = R7 (verified BN=128 paired-strip structure) with the spill inducers
// removed: prefetch in 16 NAMED f32x4 scalars (no local-array pointers),
// commit via by-value lambdas, V-prefetch moved late to shorten liveness.

typedef __bf16 bf16x8 __attribute__((ext_vector_type(8)));
typedef __bf16 bf16x4 __attribute__((ext_vector_type(4)));
typedef __bf16 bf16x2 __attribute__((ext_vector_type(2)));
typedef float  f32x4  __attribute__((ext_vector_type(4)));

#define MFMA16(a, b, c) __builtin_amdgcn_mfma_f32_16x16x32_bf16((a), (b), (c), 0, 0, 0)

static constexpr int S  = 2048;
static constexpr int H  = 16;
static constexpr int D  = 64;
static constexpr int RS = 3 * H * D;   // 3072 floats between consecutive s rows
static constexpr int BN = 128;         // key rows per iteration (2 x 64 halves)
static constexpr int LR = 72;          // row stride (u16) for 64-col tiles
static constexpr int LW = 136;         // row stride (u16) for 128-col tiles

// load one 64-row sub-tile slice (2 rows x 8 cols per thread) into 4 scalars
#define LOAD4(d0, d1, d2, d3, base, s0)                                   \
    {                                                                     \
        const float* pg_ = (base) + (size_t)((s0) + r2) * RS + cb;        \
        d0 = *(const f32x4*)(pg_);                                        \
        d1 = *(const f32x4*)(pg_ + 4);                                    \
        d2 = *(const f32x4*)(pg_ + RS);                                   \
        d3 = *(const f32x4*)(pg_ + RS + 4);                               \
    }

__global__ __launch_bounds__(256, 2)
void ttt_kernel_r8(const float* __restrict__ qkv, float* __restrict__ out)
{
    __shared__ __bf16 ldsS[128 * LR];  // Q staging (stride LR) -> per-wave scratch (stride LW)
    __shared__ __bf16 ldsK[BN * LR];   // K tile row-major [s][d], 128 rows
    __shared__ __bf16 ldsW[D  * LW];   // W^T [d][ (s&64) + ((s&63) ^ (d&56)) ]

    const int tid  = threadIdx.x;
    const int wv   = tid >> 6;
    const int lane = tid & 63;
    const int q    = lane >> 4;        // quad 0..3
    const int l16  = lane & 15;

    // i bits: [2:0]=bh_low (XCD pin), [6:3]=p, [8:7]=bh_high
    const int i  = (int)blockIdx.x;
    const int p  = (i >> 3) & 15;
    const int bh = (i & 7) + 8 * (i >> 7);
    const int b  = bh >> 4;
    const int h  = bh & 15;
    const int tA = 64 * p;             // light strip
    const int tB = 64 * (31 - p);      // heavy strip
    const int nA2 = (p >> 1) + 1;      // 128-wide s-blocks for strip A
    const int nB2 = (33 - p) >> 1;     // 128-wide s-blocks for strip B (>= nA2)

    const float* baseQ = qkv + (size_t)b * S * RS + h * D;
    const float* baseK = baseQ + H * D;
    const float* baseV = baseQ + 2 * H * D;

    // staging coords: thread owns rows r2,r2+1 cols cb..cb+7 of a 64x64 sub-tile
    const int r2 = (tid >> 3) * 2;
    const int cb = (tid & 7) * 8;

    // ---- stage Q for both strips (128 rows) -> ldsS row-major [t][d], stride LR ----
    {
        const int r   = tid >> 1;
        const int gr  = (r < 64) ? (tA + r) : (tB + r - 64);
        const int cbq = (tid & 1) * 32;
        const float* pq = baseQ + (size_t)gr * RS + cbq;
        __bf16* dst = ldsS + r * LR + cbq;
#pragma unroll
        for (int u = 0; u < 4; ++u) {
            f32x4 f0 = *(const f32x4*)(pq + u * 8);
            f32x4 f1 = *(const f32x4*)(pq + u * 8 + 4);
            bf16x8 w;
#pragma unroll
            for (int j = 0; j < 4; ++j) { w[j] = (__bf16)f0[j]; w[4 + j] = (__bf16)f1[j]; }
            *(bf16x8*)(dst + u * 8) = w;
        }
    }

    // prefetch regs: NAMED scalars only (no arrays -> no SROA failure/spill)
    f32x4 pk0, pk1, pk2, pk3, pk4, pk5, pk6, pk7;
    f32x4 pv0, pv1, pv2, pv3, pv4, pv5, pv6, pv7;

    // commit helpers (by-value args; all LDS indices compile-time after inline)
    auto commitK = [&](int half, f32x4 a0, f32x4 a1, f32x4 a2, f32x4 a3) {
        bf16x8 w0, w1;
#pragma unroll
        for (int jj = 0; jj < 4; ++jj) {
            w0[jj] = (__bf16)a0[jj]; w0[4 + jj] = (__bf16)a1[jj];
            w1[jj] = (__bf16)a2[jj]; w1[4 + jj] = (__bf16)a3[jj];
        }
        *(bf16x8*)(ldsK + (64 * half + r2) * LR + cb)     = w0;
        *(bf16x8*)(ldsK + (64 * half + r2 + 1) * LR + cb) = w1;
    };
    auto commitW = [&](int half, f32x4 a0, f32x4 a1, f32x4 a2, f32x4 a3) {
#pragma unroll
        for (int jj = 0; jj < 8; ++jj) {
            const int d = cb + jj;
            bf16x2 w;
            w[0] = (__bf16)((jj < 4) ? a0[jj & 3] : a1[jj & 3]);
            w[1] = (__bf16)((jj < 4) ? a2[jj & 3] : a3[jj & 3]);
            *(bf16x2*)(ldsW + d * LW + 64 * half + (r2 ^ (d & 56))) = w;
        }
    };

    LOAD4(pk0, pk1, pk2, pk3, baseK, 0);
    LOAD4(pk4, pk5, pk6, pk7, baseK, 64);

    __syncthreads();   // Q staged

    // ---- hoist X B-frags: lane holds X[t = base+l16][d = kt*32+q*8+j] ----
    bf16x8 Xf[2][2];   // [strip][kt]
    const int rowA = wv * 16;
    const int rowB = 64 + wv * 16;
#pragma unroll
    for (int kt = 0; kt < 2; ++kt) {
        Xf[0][kt] = *(bf16x8*)(ldsS + (rowA + l16) * LR + kt * 32 + q * 8);
        Xf[1][kt] = *(bf16x8*)(ldsS + (rowB + l16) * LR + kt * 32 + q * 8);
    }
    __bf16* sc = ldsS + (wv * 16) * LW;   // wave-private scratch, 16 rows x LW
    const int rot = 8 * l16;              // P-region rotation swizzle (mod 128)

    const f32x4 zero4 = {0.f, 0.f, 0.f, 0.f};
    f32x4 Y[2][4];                     // [strip][nd]
#pragma unroll
    for (int st = 0; st < 2; ++st)
#pragma unroll
        for (int nd = 0; nd < 4; ++nd) Y[st][nd] = zero4;

    for (int pass = 0; pass < 2; ++pass) {
        for (int jb = 0; jb < nB2; ++jb) {
            __syncthreads();                       // prior iter's tile reads done
            // ---- commit prefetched 128-row tile to LDS ----
            commitK(0, pk0, pk1, pk2, pk3);
            commitK(1, pk4, pk5, pk6, pk7);
            if (pass == 0) {
                commitW(0, pk0, pk1, pk2, pk3);
                commitW(1, pk4, pk5, pk6, pk7);
            } else {
                commitW(0, pv0, pv1, pv2, pv3);
                commitW(1, pv4, pv5, pv6, pv7);
            }
            __syncthreads();                       // tile visible

            // ---- prefetch next K tile (drains at next commit) ----
            if (jb + 1 < nB2) {
                LOAD4(pk0, pk1, pk2, pk3, baseK, 128 * (jb + 1));
                LOAD4(pk4, pk5, pk6, pk7, baseK, 128 * (jb + 1) + 64);
            } else if (pass == 0) {
                LOAD4(pk0, pk1, pk2, pk3, baseK, 0);
                LOAD4(pk4, pk5, pk6, pk7, baseK, 64);
            }

            const bool actA = (jb < nA2);          // block-uniform branch

            // ---- GEMM1-T both strips (shared kf): Pt[s][t] = sum_d K[s][d] X[t][d] ----
            f32x4 PtA[8], PtB[8];
#pragma unroll
            for (int mi = 0; mi < 8; ++mi) { PtA[mi] = zero4; PtB[mi] = zero4; }
#pragma unroll
            for (int kt = 0; kt < 2; ++kt) {
#pragma unroll
                for (int mi = 0; mi < 8; ++mi) {
                    bf16x8 kf = *(bf16x8*)(ldsK + (mi * 16 + l16) * LR + kt * 32 + q * 8);
                    PtB[mi] = MFMA16(kf, Xf[1][kt], PtB[mi]);
                    if (actA) PtA[mi] = MFMA16(kf, Xf[0][kt], PtA[mi]);
                }
            }

            // ---- strip B: mask + pack + b64 store, then GEMM2 ----
            {
                const int tgB = tB + wv * 16 + l16;
#pragma unroll
                for (int mi = 0; mi < 8; ++mi) {
                    const int sg0 = jb * BN + mi * 16 + q * 4;
                    bf16x4 pw;
#pragma unroll
                    for (int r = 0; r < 4; ++r)
                        pw[r] = (__bf16)((sg0 + r <= tgB) ? PtB[mi][r] : 0.0f);
                    *(bf16x4*)(sc + l16 * LW + ((mi * 16 + q * 4 + rot) & 127)) = pw;
                }
#pragma unroll
                for (int kt = 0; kt < 4; ++kt) {
                    bf16x8 af = *(bf16x8*)(sc + l16 * LW + ((kt * 32 + q * 8 + rot) & 127));
#pragma unroll
                    for (int nd = 0; nd < 4; ++nd) {
                        const int d = l16 + nd * 16;
                        const int o = kt * 32 + q * 8;
                        bf16x8 wf = *(bf16x8*)(ldsW + d * LW + (o & 64) + ((o & 63) ^ (d & 56)));
                        Y[1][nd] = MFMA16(af, wf, Y[1][nd]);
                    }
                }
            }

            // ---- prefetch next V tile late (short liveness; used next commit) ----
            if (pass == 1) {
                if (jb + 1 < nB2) {
                    LOAD4(pv0, pv1, pv2, pv3, baseV, 128 * (jb + 1));
                    LOAD4(pv4, pv5, pv6, pv7, baseV, 128 * (jb + 1) + 64);
                }
            } else if (jb == nB2 - 1) {
                LOAD4(pv0, pv1, pv2, pv3, baseV, 0);
                LOAD4(pv4, pv5, pv6, pv7, baseV, 64);
            }

            // ---- strip A: same, reusing the wave-private scratch ----
            if (actA) {
                const int tgA = tA + wv * 16 + l16;
#pragma unroll
                for (int mi = 0; mi < 8; ++mi) {
                    const int sg0 = jb * BN + mi * 16 + q * 4;
                    bf16x4 pw;
#pragma unroll
                    for (int r = 0; r < 4; ++r)
                        pw[r] = (__bf16)((sg0 + r <= tgA) ? PtA[mi][r] : 0.0f);
                    *(bf16x4*)(sc + l16 * LW + ((mi * 16 + q * 4 + rot) & 127)) = pw;
                }
#pragma unroll
                for (int kt = 0; kt < 4; ++kt) {
                    bf16x8 af = *(bf16x8*)(sc + l16 * LW + ((kt * 32 + q * 8 + rot) & 127));
#pragma unroll
                    for (int nd = 0; nd < 4; ++nd) {
                        const int d = l16 + nd * 16;
                        const int o = kt * 32 + q * 8;
                        bf16x8 wf = *(bf16x8*)(ldsW + d * LW + (o & 64) + ((o & 63) ^ (d & 56)));
                        Y[0][nd] = MFMA16(af, wf, Y[0][nd]);
                    }
                }
            }
        }

        if (pass == 0) {
            // per strip: o2 (C-layout) -> wave-private scratch plain [t][d],
            // reread as B-frags, Xf = 2Q - o2; reset Y. Sequential strips reuse sc.
#pragma unroll
            for (int st = 0; st < 2; ++st) {
#pragma unroll
                for (int nd = 0; nd < 4; ++nd)
#pragma unroll
                    for (int r = 0; r < 4; ++r)
                        sc[(q * 4 + r) * LW + l16 + nd * 16] = (__bf16)Y[st][nd][r];
#pragma unroll
                for (int kt = 0; kt < 2; ++kt) {
                    bf16x8 of = *(bf16x8*)(sc + l16 * LW + kt * 32 + q * 8);
#pragma unroll
                    for (int jj = 0; jj < 8; ++jj)
                        Xf[st][kt][jj] = (__bf16)(2.0f * (float)Xf[st][kt][jj] - (float)of[jj]);
                }
#pragma unroll
                for (int nd = 0; nd < 4; ++nd) Y[st][nd] = zero4;
            }
        } else {
            // out[b][t][h][d] fp32, both strips
#pragma unroll
            for (int st = 0; st < 2; ++st) {
                const int tb = (st == 0) ? tA : tB;
#pragma unroll
                for (int nd = 0; nd < 4; ++nd)
#pragma unroll
                    for (int r = 0; r < 4; ++r) {
                        const int t = tb + wv * 16 + q * 4 + r;
                        const int d = l16 + nd * 16;
                        out[(((size_t)b * S + t) * H + h) * D + d] = Y[st][nd][r];
                    }
            }
        }
    }
}

extern "C" void kernel_launch(void* const* d_in, const int* in_sizes, int n_in,
                              void* d_out, int out_size, void* d_ws, size_t ws_size,
                              hipStream_t stream)
{
    const float* qkv = (const float*)d_in[0];
    float* out = (float*)d_out;
    ttt_kernel_r8<<<dim3(512), 256, 0, stream>>>(qkv, out);   // 16 pairs x 32 bh
}

// Round 9
// 232.004 us; speedup vs baseline: 2.0549x; 2.0549x over previous
//
#include <hip/hip_runtime.h>
#include <hip/hip_bf16.h>

// out = tril((2Q - tril(QK^T)K) K^T) V per (b,h): two fused causal passes of
// Y = tril(X K^T) W  (pass0: X=Q,W=K -> o2; pass1: X=2Q-o2, W=V).
// R9 = R4 register footprint + BN=128 barrier-pairs: two 64-row halves staged
// per barrier pair, processed SEQUENTIALLY (Pt[4] reused, R4's 64-col wave
// scratch reused per half) -> half the barrier events at R4's register cost.

typedef __bf16 bf16x8 __attribute__((ext_vector_type(8)));
typedef __bf16 bf16x4 __attribute__((ext_vector_type(4)));
typedef __bf16 bf16x2 __attribute__((ext_vector_type(2)));
typedef float  f32x4  __attribute__((ext_vector_type(4)));

#define MFMA16(a, b, c) __builtin_amdgcn_mfma_f32_16x16x32_bf16((a), (b), (c), 0, 0, 0)

static constexpr int S  = 2048;
static constexpr int H  = 16;
static constexpr int D  = 64;
static constexpr int RS = 3 * H * D;   // 3072 floats between consecutive s rows
static constexpr int LR = 72;          // row stride (u16) for 64-col regions
static constexpr int LW = 136;         // row stride (u16) for the 128-col W^T

// load one 64-row sub-tile slice (2 rows x 8 cols per thread) into 4 named regs
#define LOAD4(d0, d1, d2, d3, base, s0)                                   \
    {                                                                     \
        const float* pg_ = (base) + (size_t)((s0) + r2) * RS + cb;        \
        d0 = *(const f32x4*)(pg_);                                        \
        d1 = *(const f32x4*)(pg_ + 4);                                    \
        d2 = *(const f32x4*)(pg_ + RS);                                   \
        d3 = *(const f32x4*)(pg_ + RS + 4);                               \
    }

__global__ __launch_bounds__(256)
void ttt_kernel_r9(const float* __restrict__ qkv, float* __restrict__ out)
{
    __shared__ __bf16 ldsS[128 * LR];  // Q staging -> per-wave P/o2 scratch (R4-exact)
    __shared__ __bf16 ldsK[128 * LR];  // K tile row-major [s][d], 128 rows
    __shared__ __bf16 ldsW[D * LW];    // W^T [d][ 64*half + ((s&63) ^ (d&56)) ]

    const int tid  = threadIdx.x;
    const int wv   = tid >> 6;
    const int lane = tid & 63;
    const int q    = lane >> 4;        // quad 0..3
    const int l16  = lane & 15;

    // i bits: [2:0]=bh_low (XCD pin), [6:3]=p, [8:7]=bh_high
    const int i  = (int)blockIdx.x;
    const int p  = (i >> 3) & 15;
    const int bh = (i & 7) + 8 * (i >> 7);
    const int b  = bh >> 4;
    const int h  = bh & 15;
    const int tA = 64 * p;             // light strip
    const int tB = 64 * (31 - p);      // heavy strip
    const int nA = p + 1;              // 64-row s-blocks for strip A
    const int nB = 32 - p;             // 64-row s-blocks for strip B (>= nA)
    const int nB2 = (nB + 1) >> 1;     // barrier-pair iterations

    const float* baseQ = qkv + (size_t)b * S * RS + h * D;
    const float* baseK = baseQ + H * D;
    const float* baseV = baseQ + 2 * H * D;

    // staging coords: thread owns rows r2,r2+1 cols cb..cb+7 of a 64x64 sub-tile
    const int r2 = (tid >> 3) * 2;
    const int cb = (tid & 7) * 8;

    // ---- stage Q for both strips (128 rows) -> ldsS row-major [t][d] ----
    {
        const int r   = tid >> 1;
        const int gr  = (r < 64) ? (tA + r) : (tB + r - 64);
        const int cbq = (tid & 1) * 32;
        const float* pq = baseQ + (size_t)gr * RS + cbq;
        __bf16* dst = ldsS + r * LR + cbq;
#pragma unroll
        for (int u = 0; u < 4; ++u) {
            f32x4 f0 = *(const f32x4*)(pq + u * 8);
            f32x4 f1 = *(const f32x4*)(pq + u * 8 + 4);
            bf16x8 w;
#pragma unroll
            for (int j = 0; j < 4; ++j) { w[j] = (__bf16)f0[j]; w[4 + j] = (__bf16)f1[j]; }
            *(bf16x8*)(dst + u * 8) = w;
        }
    }

    // prefetch regs: named scalars (no local-array pointers)
    f32x4 pk0, pk1, pk2, pk3, pk4, pk5, pk6, pk7;
    f32x4 pv0, pv1, pv2, pv3, pv4, pv5, pv6, pv7;

    auto commitK = [&](int half, f32x4 a0, f32x4 a1, f32x4 a2, f32x4 a3) {
        bf16x8 w0, w1;
#pragma unroll
        for (int jj = 0; jj < 4; ++jj) {
            w0[jj] = (__bf16)a0[jj]; w0[4 + jj] = (__bf16)a1[jj];
            w1[jj] = (__bf16)a2[jj]; w1[4 + jj] = (__bf16)a3[jj];
        }
        *(bf16x8*)(ldsK + (64 * half + r2) * LR + cb)     = w0;
        *(bf16x8*)(ldsK + (64 * half + r2 + 1) * LR + cb) = w1;
    };
    auto commitW = [&](int half, f32x4 a0, f32x4 a1, f32x4 a2, f32x4 a3) {
#pragma unroll
        for (int jj = 0; jj < 8; ++jj) {
            const int d = cb + jj;
            bf16x2 w;
            w[0] = (__bf16)((jj < 4) ? a0[jj & 3] : a1[jj & 3]);
            w[1] = (__bf16)((jj < 4) ? a2[jj & 3] : a3[jj & 3]);
            *(bf16x2*)(ldsW + d * LW + 64 * half + (r2 ^ (d & 56))) = w;
        }
    };

    LOAD4(pk0, pk1, pk2, pk3, baseK, 0);
    LOAD4(pk4, pk5, pk6, pk7, baseK, 64);

    __syncthreads();   // Q staged

    // ---- hoist X B-frags: lane holds X[t = base+l16][d = kt*32+q*8+j] ----
    bf16x8 Xf[2][2];   // [strip][kt]
    const int rowA = wv * 16;
    const int rowB = 64 + wv * 16;
#pragma unroll
    for (int kt = 0; kt < 2; ++kt) {
        Xf[0][kt] = *(bf16x8*)(ldsS + (rowA + l16) * LR + kt * 32 + q * 8);
        Xf[1][kt] = *(bf16x8*)(ldsS + (rowB + l16) * LR + kt * 32 + q * 8);
    }
    __bf16* sA = ldsS + rowA * LR;     // wave-private scratch, strip A (16 rows)
    __bf16* sB = ldsS + rowB * LR;     // wave-private scratch, strip B
    const int rot = 8 * l16;           // P-region rotation swizzle

    const f32x4 zero4 = {0.f, 0.f, 0.f, 0.f};
    f32x4 Y[2][4];                     // [strip][nd]
#pragma unroll
    for (int st = 0; st < 2; ++st)
#pragma unroll
        for (int nd = 0; nd < 4; ++nd) Y[st][nd] = zero4;

    for (int pass = 0; pass < 2; ++pass) {
        for (int jb = 0; jb < nB2; ++jb) {
            __syncthreads();                       // prior pair's tile reads done
            // ---- commit 128-row tile (both halves) ----
            commitK(0, pk0, pk1, pk2, pk3);
            commitK(1, pk4, pk5, pk6, pk7);
            if (pass == 0) {
                commitW(0, pk0, pk1, pk2, pk3);
                commitW(1, pk4, pk5, pk6, pk7);
            } else {
                commitW(0, pv0, pv1, pv2, pv3);
                commitW(1, pv4, pv5, pv6, pv7);
            }
            __syncthreads();                       // tile visible

            // ---- prefetch next 128-row tile (drains a full pair later) ----
            if (jb + 1 < nB2) {
                LOAD4(pk0, pk1, pk2, pk3, baseK, 128 * (jb + 1));
                LOAD4(pk4, pk5, pk6, pk7, baseK, 128 * (jb + 1) + 64);
                if (pass == 1) {
                    LOAD4(pv0, pv1, pv2, pv3, baseV, 128 * (jb + 1));
                    LOAD4(pv4, pv5, pv6, pv7, baseV, 128 * (jb + 1) + 64);
                }
            } else if (pass == 0) {
                LOAD4(pk0, pk1, pk2, pk3, baseK, 0);
                LOAD4(pk4, pk5, pk6, pk7, baseK, 64);
                LOAD4(pv0, pv1, pv2, pv3, baseV, 0);
                LOAD4(pv4, pv5, pv6, pv7, baseV, 64);
            }

            // ---- two 64-row halves, sequential (R4 inner body each) ----
#pragma unroll
            for (int hf = 0; hf < 2; ++hf) {
                const int sb = 2 * jb + hf;
                if (sb >= nB) break;               // block-uniform
                const bool actA = (sb < nA);

                // GEMM1-T both strips: Pt[s][t] = sum_d K[s][d] X[t][d]
                f32x4 PtA[4], PtB[4];
#pragma unroll
                for (int mi = 0; mi < 4; ++mi) { PtA[mi] = zero4; PtB[mi] = zero4; }
#pragma unroll
                for (int kt = 0; kt < 2; ++kt) {
#pragma unroll
                    for (int mi = 0; mi < 4; ++mi) {
                        bf16x8 kf = *(bf16x8*)(ldsK + (64 * hf + mi * 16 + l16) * LR + kt * 32 + q * 8);
                        PtB[mi] = MFMA16(kf, Xf[1][kt], PtB[mi]);
                        if (actA) PtA[mi] = MFMA16(kf, Xf[0][kt], PtA[mi]);
                    }
                }

                // mask + pack + b64 store: s?[t_local][(s + 8*l16)&63]
                {
                    const int tgB = tB + wv * 16 + l16;
                    const int tgA = tA + wv * 16 + l16;
#pragma unroll
                    for (int mi = 0; mi < 4; ++mi) {
                        const int sg0 = sb * 64 + mi * 16 + q * 4;
                        bf16x4 pwB;
#pragma unroll
                        for (int r = 0; r < 4; ++r)
                            pwB[r] = (__bf16)((sg0 + r <= tgB) ? PtB[mi][r] : 0.0f);
                        *(bf16x4*)(sB + l16 * LR + ((mi * 16 + q * 4 + rot) & 63)) = pwB;
                        if (actA) {
                            bf16x4 pwA;
#pragma unroll
                            for (int r = 0; r < 4; ++r)
                                pwA[r] = (__bf16)((sg0 + r <= tgA) ? PtA[mi][r] : 0.0f);
                            *(bf16x4*)(sA + l16 * LR + ((mi * 16 + q * 4 + rot) & 63)) = pwA;
                        }
                    }
                }

                // GEMM2 both strips: Y[t][d] += sum_s P[t][s] W[s][d]
#pragma unroll
                for (int kt = 0; kt < 2; ++kt) {
                    bf16x8 afB = *(bf16x8*)(sB + l16 * LR + ((kt * 32 + q * 8 + rot) & 63));
                    bf16x8 afA;
                    if (actA) afA = *(bf16x8*)(sA + l16 * LR + ((kt * 32 + q * 8 + rot) & 63));
#pragma unroll
                    for (int nd = 0; nd < 4; ++nd) {
                        const int d = l16 + nd * 16;
                        bf16x8 wf = *(bf16x8*)(ldsW + d * LW + 64 * hf + ((kt * 32 + q * 8) ^ (d & 56)));
                        Y[1][nd] = MFMA16(afB, wf, Y[1][nd]);
                        if (actA) Y[0][nd] = MFMA16(afA, wf, Y[0][nd]);
                    }
                }
            }
        }

        if (pass == 0) {
            // per strip: o2 (C-layout) -> wave-private scratch plain [t][d],
            // reread as B-frags, Xf = 2Q - o2; reset Y. No barrier needed.
#pragma unroll
            for (int st = 0; st < 2; ++st) {
                __bf16* scp = (st == 0) ? sA : sB;
#pragma unroll
                for (int nd = 0; nd < 4; ++nd)
#pragma unroll
                    for (int r = 0; r < 4; ++r)
                        scp[(q * 4 + r) * LR + l16 + nd * 16] = (__bf16)Y[st][nd][r];
#pragma unroll
                for (int kt = 0; kt < 2; ++kt) {
                    bf16x8 of = *(bf16x8*)(scp + l16 * LR + kt * 32 + q * 8);
#pragma unroll
                    for (int jj = 0; jj < 8; ++jj)
                        Xf[st][kt][jj] = (__bf16)(2.0f * (float)Xf[st][kt][jj] - (float)of[jj]);
                }
#pragma unroll
                for (int nd = 0; nd < 4; ++nd) Y[st][nd] = zero4;
            }
        } else {
            // out[b][t][h][d] fp32, both strips
#pragma unroll
            for (int st = 0; st < 2; ++st) {
                const int tb = (st == 0) ? tA : tB;
#pragma unroll
                for (int nd = 0; nd < 4; ++nd)
#pragma unroll
                    for (int r = 0; r < 4; ++r) {
                        const int t = tb + wv * 16 + q * 4 + r;
                        const int d = l16 + nd * 16;
                        out[(((size_t)b * S + t) * H + h) * D + d] = Y[st][nd][r];
                    }
            }
        }
    }
}

extern "C" void kernel_launch(void* const* d_in, const int* in_sizes, int n_in,
                              void* d_out, int out_size, void* d_ws, size_t ws_size,
                              hipStream_t stream)
{
    const float* qkv = (const float*)d_in[0];
    float* out = (float*)d_out;
    ttt_kernel_r9<<<dim3(512), 256, 0, stream>>>(qkv, out);   // 16 pairs x 32 bh
}